// Round 6
// baseline (252.328 us; speedup 1.0000x reference)
//
#include <hip/hip_runtime.h>
#include <math.h>

#define NB 16
#define NCIN 64
#define NCOUT 64
#define NH 256
#define NW 256
#define NM 64          // 2*M1 row modes
#define NKX 32         // M2 retained columns
#define INV256 (1.0f/256.0f)

typedef __attribute__((ext_vector_type(8))) short short8v;
typedef __attribute__((ext_vector_type(4))) float f32x4;
typedef unsigned short u16;
typedef unsigned int u32;

__device__ __forceinline__ void bf16_split(float v, u16& hi, u16& lo) {
    u32 b = __float_as_uint(v);
    u32 hib = b & 0xffff0000u;
    float lof = v - __uint_as_float(hib);
    hi = (u16)(hib >> 16);
    lo = (u16)(__float_as_uint(lof) >> 16);
}

__device__ __forceinline__ u16 bf16_rtn(float v) {
    u32 b = __float_as_uint(v);
    u32 r = b + 0x7fffu + ((b >> 16) & 1u);
    return (u16)(r >> 16);
}

// ---------------- fwd twiddle tables (dedicated region @ ws+48MiB) ----------
//  T1h @ 0      T1l @ 16384   : [kc 8][nt 4][lane 64][e 8]  (phase-1 B frags)
//  C2h @ 32768  C2l @ 49152   : [mt 4][kc 8][lane 64][e 8]  (phase-2 A frags)
//  S2h @ 65536  S2l @ 81920
//  Snh @ 98304  Snl @ 114688
__global__ __launch_bounds__(256) void init_tw(u16* __restrict__ tw) {
    const int tid = blockIdx.x * 256 + threadIdx.x;   // 0..32767
    const float TWO_PI = 6.28318530717958647692f;
    if (tid < 16384) {
        const int e = tid & 7, lane = (tid >> 3) & 63;
        const int nt = (tid >> 9) & 3, kc = tid >> 11;
        const int w = kc * 32 + (lane >> 4) * 8 + e;
        const int n = nt * 16 + (lane & 15);
        const int kx = n >> 1, p = n & 1;
        const float ang = TWO_PI * (float)((kx * w) & 255) * INV256;
        const float v = p ? -sinf(ang) : cosf(ang);
        u16 hi, lo; bf16_split(v, hi, lo);
        tw[tid] = hi; tw[16384 + tid] = lo;
    } else {
        const int u = tid - 16384;
        const int e = u & 7, lane = (u >> 3) & 63;
        const int kc = (u >> 9) & 7, mt = u >> 12;
        const int m = mt * 16 + (lane & 15);
        const int h = kc * 32 + (lane >> 4) * 8 + e;
        const int ky = (m < 32) ? m : (192 + m);
        const float ang = TWO_PI * (float)((ky * h) & 255) * INV256;
        const float c = cosf(ang), s = sinf(ang);
        u16 hi, lo;
        bf16_split(c,  hi, lo); tw[32768 + u] = hi; tw[49152 + u]  = lo;
        bf16_split(s,  hi, lo); tw[65536 + u] = hi; tw[81920 + u]  = lo;
        bf16_split(-s, hi, lo); tw[98304 + u] = hi; tw[114688 + u] = lo;
    }
}

// ---------------- inv twiddle tables (own region, after tw) -----------------
//  C4 @ 0      S4 @ 16384    N4 @ 32768 : [HT 16][kc 2][lane 64][e 8]
//  W5 @ 49152                           : [wt 16][kc 2][lane 64][e 8]
//  W5 serves as A-frag (row=w=lane&15) AND B-frag (col=w) — same mapping.
//  k-order interleaved: kk = 2*kx + c; c=0 -> wt*cos/256, c=1 -> -wt*sin/256
__global__ __launch_bounds__(256) void init_tw2(u16* __restrict__ tw2) {
    const int tid = blockIdx.x * 256 + threadIdx.x;   // 0..32767
    const float TWO_PI = 6.28318530717958647692f;
    if (tid < 16384) {
        const int e = tid & 7, lane = (tid >> 3) & 63;
        const int kc = (tid >> 9) & 1, HT = tid >> 10;
        const int h = HT * 16 + (lane & 15);
        const int m = kc * 32 + ((lane >> 4) << 3) + e;
        const int ky = (m < 32) ? m : (192 + m);
        const float ang = TWO_PI * (float)((ky * h) & 255) * INV256;
        tw2[tid]         = bf16_rtn(cosf(ang));
        tw2[16384 + tid] = bf16_rtn(sinf(ang));
        tw2[32768 + tid] = bf16_rtn(-sinf(ang));
    } else {
        const int u = tid - 16384;
        const int e = u & 7, lane = (u >> 3) & 63;
        const int kc = (u >> 9) & 1, nt = u >> 10;
        const int w = nt * 16 + (lane & 15);
        const int kk = kc * 32 + ((lane >> 4) << 3) + e;
        const int kx = kk >> 1, c = kk & 1;
        const float wt = (kx == 0) ? 1.f : 2.f;
        const float ang = TWO_PI * (float)((kx * w) & 255) * INV256;
        const float v = c ? (-wt * sinf(ang) * INV256) : (wt * cosf(ang) * INV256);
        tw2[49152 + u] = bf16_rtn(v);
    }
}

// ---------------- Kernel 1: forward partial rfft2 via MFMA ----------------
__global__ __launch_bounds__(256) void fwd_mfma(const float* __restrict__ x,
                                                const u16* __restrict__ tw,
                                                float2* __restrict__ xft) {
    __shared__ u16 planes[4 * 32 * 264];   // 67584 B
    const int t = threadIdx.x;
    const int lane = t & 63;
    const int wv = t >> 6;
    const int l15 = lane & 15;
    const int lk = lane >> 4;
    const float* __restrict__ xb = x + (size_t)blockIdx.x * (NH * NW);

    const u16* __restrict__ T1h = tw;
    const u16* __restrict__ T1l = tw + 16384;

    for (int mt = 0; mt < 4; ++mt) {
        const int hbase = wv * 64 + mt * 16;
        f32x4 acc[4] = {f32x4{0,0,0,0}, f32x4{0,0,0,0}, f32x4{0,0,0,0}, f32x4{0,0,0,0}};
        for (int kc = 0; kc < 8; ++kc) {
            const float* xr = xb + (size_t)(hbase + l15) * NW + kc * 32 + lk * 8;
            const float4 xa = *(const float4*)xr;
            const float4 xc = *(const float4*)(xr + 4);
            const float v[8] = {xa.x, xa.y, xa.z, xa.w, xc.x, xc.y, xc.z, xc.w};
            short8v Ah, Al;
            #pragma unroll
            for (int e = 0; e < 8; ++e) {
                u16 hi, lo; bf16_split(v[e], hi, lo);
                Ah[e] = (short)hi; Al[e] = (short)lo;
            }
            const int tbase = (kc * 4) * 512 + lane * 8;
            #pragma unroll
            for (int nt = 0; nt < 4; ++nt) {
                const short8v Bh = *(const short8v*)(T1h + tbase + nt * 512);
                const short8v Bl = *(const short8v*)(T1l + tbase + nt * 512);
                acc[nt] = __builtin_amdgcn_mfma_f32_16x16x32_bf16(Ah, Bh, acc[nt], 0, 0, 0);
                acc[nt] = __builtin_amdgcn_mfma_f32_16x16x32_bf16(Ah, Bl, acc[nt], 0, 0, 0);
                acc[nt] = __builtin_amdgcn_mfma_f32_16x16x32_bf16(Al, Bh, acc[nt], 0, 0, 0);
            }
        }
        #pragma unroll
        for (int nt = 0; nt < 4; ++nt) {
            const int n = nt * 16 + l15;
            const int kx = n >> 1, p = n & 1;
            #pragma unroll
            for (int r = 0; r < 4; ++r) {
                const int h = hbase + lk * 4 + r;
                u16 hi, lo; bf16_split(acc[nt][r], hi, lo);
                planes[(2 * p) * 8448 + kx * 264 + h] = hi;
                planes[(2 * p + 1) * 8448 + kx * 264 + h] = lo;
            }
        }
    }
    __syncthreads();

    const u16* __restrict__ C2h = tw + 32768;
    const u16* __restrict__ C2l = tw + 49152;
    const u16* __restrict__ S2h = tw + 65536;
    const u16* __restrict__ S2l = tw + 81920;
    const u16* __restrict__ Snh = tw + 98304;
    const u16* __restrict__ Snl = tw + 114688;

    f32x4 zre[2] = {f32x4{0,0,0,0}, f32x4{0,0,0,0}};
    f32x4 zim[2] = {f32x4{0,0,0,0}, f32x4{0,0,0,0}};
    for (int kc = 0; kc < 8; ++kc) {
        const int abase = (wv * 8 + kc) * 512 + lane * 8;
        const short8v Ch = *(const short8v*)(C2h + abase);
        const short8v Cl = *(const short8v*)(C2l + abase);
        const short8v Sh = *(const short8v*)(S2h + abase);
        const short8v Sl = *(const short8v*)(S2l + abase);
        const short8v Nh = *(const short8v*)(Snh + abase);
        const short8v Nl = *(const short8v*)(Snl + abase);
        #pragma unroll
        for (int nt = 0; nt < 2; ++nt) {
            const int kx = nt * 16 + l15;
            const int off = kx * 264 + kc * 32 + lk * 8;
            const short8v Yrh = *(const short8v*)(planes + off);
            const short8v Yrl = *(const short8v*)(planes + 8448 + off);
            const short8v Yih = *(const short8v*)(planes + 16896 + off);
            const short8v Yil = *(const short8v*)(planes + 25344 + off);
            zre[nt] = __builtin_amdgcn_mfma_f32_16x16x32_bf16(Ch, Yrh, zre[nt], 0, 0, 0);
            zre[nt] = __builtin_amdgcn_mfma_f32_16x16x32_bf16(Ch, Yrl, zre[nt], 0, 0, 0);
            zre[nt] = __builtin_amdgcn_mfma_f32_16x16x32_bf16(Cl, Yrh, zre[nt], 0, 0, 0);
            zre[nt] = __builtin_amdgcn_mfma_f32_16x16x32_bf16(Sh, Yih, zre[nt], 0, 0, 0);
            zre[nt] = __builtin_amdgcn_mfma_f32_16x16x32_bf16(Sh, Yil, zre[nt], 0, 0, 0);
            zre[nt] = __builtin_amdgcn_mfma_f32_16x16x32_bf16(Sl, Yih, zre[nt], 0, 0, 0);
            zim[nt] = __builtin_amdgcn_mfma_f32_16x16x32_bf16(Ch, Yih, zim[nt], 0, 0, 0);
            zim[nt] = __builtin_amdgcn_mfma_f32_16x16x32_bf16(Ch, Yil, zim[nt], 0, 0, 0);
            zim[nt] = __builtin_amdgcn_mfma_f32_16x16x32_bf16(Cl, Yih, zim[nt], 0, 0, 0);
            zim[nt] = __builtin_amdgcn_mfma_f32_16x16x32_bf16(Nh, Yrh, zim[nt], 0, 0, 0);
            zim[nt] = __builtin_amdgcn_mfma_f32_16x16x32_bf16(Nh, Yrl, zim[nt], 0, 0, 0);
            zim[nt] = __builtin_amdgcn_mfma_f32_16x16x32_bf16(Nl, Yrh, zim[nt], 0, 0, 0);
        }
    }
    float2* __restrict__ op = xft + (size_t)blockIdx.x * (NM * NKX);
    #pragma unroll
    for (int nt = 0; nt < 2; ++nt) {
        const int kx = nt * 16 + l15;
        #pragma unroll
        for (int r = 0; r < 4; ++r) {
            const int m = wv * 16 + lk * 4 + r;
            op[m * NKX + kx] = make_float2(zre[nt][r] * INV256, zim[nt][r] * INV256);
        }
    }
}

// ---------------- Kernel 2: per-mode channel contraction (v4) ----------------
// grid = (m=64, og=4, kh*2+ih=8), 256 threads. i split 2-way (ih), 32 iters.
// 16B loads: wave0 loads x (float4), wave1 loads w (int4). Depth-2 reg prefetch.
// ws layout [k][o]: conflict-free b64 reads; partial sums to oft0/oft1.
__global__ __launch_bounds__(256) void mode_v4(const float2* __restrict__ xft,
                                               const int* __restrict__ q1,
                                               const int* __restrict__ q2,
                                               const float* __restrict__ w1s,
                                               const float* __restrict__ w1m,
                                               const float* __restrict__ w2s,
                                               const float* __restrict__ w2m,
                                               float2* __restrict__ oft0,
                                               float2* __restrict__ oft1) {
    __shared__ float2 xs2[2][16][8];     // [buf][b][k] — 64B rows, f4-writable
    __shared__ float2 ws2[2][8][16];     // [buf][k][o] — reads stride 8B: conflict-free
    const int m  = blockIdx.x;           // 0..63
    const int og = blockIdx.y;           // 0..3
    const int kh = blockIdx.z >> 1;      // 0..3
    const int ih = blockIdx.z & 1;       // 0..1 (i half)
    const int t = threadIdx.x;
    const int b = t >> 4, o = t & 15;
    const int mm = (m < 32) ? m : (m - 32);
    const int* __restrict__ q = (m < 32) ? q1 : q2;
    const float scale = (m < 32) ? w1s[0] : w2s[0];
    const float wmin  = (m < 32) ? w1m[0] : w2m[0];
    const int ib = ih * 32;

    const bool isx = (t < 64);
    const bool isw = (t >= 64) && (t < 128);
    const int lr = (t & 63) >> 2;        // 0..15 (b for x-loaders, o for w-loaders)
    const int kp = t & 3;                // kx-pair within kh group

    const float4* __restrict__ xsrc = (const float4*)xft
        + (size_t)(lr * 64 + ib) * 1024 + m * 16 + kh * 4 + kp;          // +1024/i
    const int4* __restrict__ wsrc = (const int4*)q
        + ((size_t)ib * 64 + og * 16 + lr) * 512 + mm * 16 + kh * 4 + kp; // +32768/i

    float4 pxa, pxb; int4 pwa, pwb;
    if (isx) {
        const float4 p0 = xsrc[0];
        *(float4*)&xs2[0][lr][kp * 2] = p0;
        pxb = xsrc[1024];
        pxa = xsrc[2048];
    } else if (isw) {
        const int4 p0 = wsrc[0];
        ws2[0][kp * 2][lr]     = make_float2(((float)p0.x + 127.f) * scale + wmin,
                                             ((float)p0.y + 127.f) * scale + wmin);
        ws2[0][kp * 2 + 1][lr] = make_float2(((float)p0.z + 127.f) * scale + wmin,
                                             ((float)p0.w + 127.f) * scale + wmin);
        pwb = wsrc[32768];
        pwa = wsrc[65536];
    }
    __syncthreads();

    float accr[8], acci[8];
    #pragma unroll
    for (int k = 0; k < 8; ++k) { accr[k] = 0.f; acci[k] = 0.f; }

    #pragma unroll 1
    for (int j = 0; j < 16; ++j) {
        // even li = 2j: compute buf0; write li+1 (pb) -> buf1
        #pragma unroll
        for (int k = 0; k < 8; ++k) {
            const float2 xv = xs2[0][b][k];
            const float2 wv = ws2[0][k][o];
            accr[k] += xv.x * wv.x - xv.y * wv.y;
            acci[k] += xv.x * wv.y + xv.y * wv.x;
        }
        if (isx) *(float4*)&xs2[1][lr][kp * 2] = pxb;
        else if (isw) {
            ws2[1][kp * 2][lr]     = make_float2(((float)pwb.x + 127.f) * scale + wmin,
                                                 ((float)pwb.y + 127.f) * scale + wmin);
            ws2[1][kp * 2 + 1][lr] = make_float2(((float)pwb.z + 127.f) * scale + wmin,
                                                 ((float)pwb.w + 127.f) * scale + wmin);
        }
        __syncthreads();
        if (2 * j + 3 < 32) {
            if (isx) pxb = xsrc[(size_t)(2 * j + 3) * 1024];
            else if (isw) pwb = wsrc[(size_t)(2 * j + 3) * 32768];
        }
        // odd li = 2j+1: compute buf1; write li+1 (pa) -> buf0
        #pragma unroll
        for (int k = 0; k < 8; ++k) {
            const float2 xv = xs2[1][b][k];
            const float2 wv = ws2[1][k][o];
            accr[k] += xv.x * wv.x - xv.y * wv.y;
            acci[k] += xv.x * wv.y + xv.y * wv.x;
        }
        if (2 * j + 2 < 32) {
            if (isx) *(float4*)&xs2[0][lr][kp * 2] = pxa;
            else if (isw) {
                ws2[0][kp * 2][lr]     = make_float2(((float)pwa.x + 127.f) * scale + wmin,
                                                     ((float)pwa.y + 127.f) * scale + wmin);
                ws2[0][kp * 2 + 1][lr] = make_float2(((float)pwa.z + 127.f) * scale + wmin,
                                                     ((float)pwa.w + 127.f) * scale + wmin);
            }
            __syncthreads();
            if (2 * j + 4 < 32) {
                if (isx) pxa = xsrc[(size_t)(2 * j + 4) * 1024];
                else if (isw) pwa = wsrc[(size_t)(2 * j + 4) * 32768];
            }
        }
    }

    float2* __restrict__ oftP = ih ? oft1 : oft0;
    float4* __restrict__ op4 = (float4*)(oftP
        + ((size_t)(b * 64 + og * 16 + o) * NM + m) * NKX + kh * 8);
    #pragma unroll
    for (int k2 = 0; k2 < 4; ++k2)
        op4[k2] = make_float4(accr[2 * k2], acci[2 * k2], accr[2 * k2 + 1], acci[2 * k2 + 1]);
}

// ---------------- Kernel 3: inverse partial irfft2 via MFMA (v2) ------------
// grid = (B*COUT, 2), 256 threads. Block handles 128 h rows.
// Phase 4: Z[128h][32kx](re,im) = twiddle[h][m] x (O0+O1)[m][kx]   (K=64)
// Phase 5 TRANSPOSED: D[w][h] = W5^T[w][kk] x Z^T[kk][h] -> dwordx4 stores.
// LDS (ushort): OrP @0 [32kx][72], OiP @2304, Zp @4608 [128hl][72]
__global__ __launch_bounds__(256) void inv_mfma2(const float2* __restrict__ oft0,
                                                 const float2* __restrict__ oft1,
                                                 const u16* __restrict__ tw2,
                                                 float* __restrict__ out) {
    __shared__ u16 lds[13824];   // 27648 B
    const int t = threadIdx.x;
    const int lane = t & 63;
    const int wv = t >> 6;
    const int l15 = lane & 15;
    const int lk = lane >> 4;
    const int hh = blockIdx.y;   // 0/1: h half

    const float4* __restrict__ p0 = (const float4*)(oft0 + (size_t)blockIdx.x * (NM * NKX));
    const float4* __restrict__ p1 = (const float4*)(oft1 + (size_t)blockIdx.x * (NM * NKX));
    #pragma unroll
    for (int rep = 0; rep < 4; ++rep) {
        const int idx4 = rep * 256 + t;
        const float4 a = p0[idx4];
        const float4 c = p1[idx4];
        const int e0 = idx4 * 2;
        const int m = e0 >> 5, kx = e0 & 31;   // kx even, kx+1 valid
        lds[kx * 72 + m]              = bf16_rtn(a.x + c.x);
        lds[2304 + kx * 72 + m]       = bf16_rtn(a.y + c.y);
        lds[(kx + 1) * 72 + m]        = bf16_rtn(a.z + c.z);
        lds[2304 + (kx + 1) * 72 + m] = bf16_rtn(a.w + c.w);
    }
    __syncthreads();

    const u16* __restrict__ C4 = tw2;
    const u16* __restrict__ S4 = tw2 + 16384;
    const u16* __restrict__ N4 = tw2 + 32768;

    short8v Br[2][2], Bi[2][2];
    #pragma unroll
    for (int nt = 0; nt < 2; ++nt) {
        #pragma unroll
        for (int kc = 0; kc < 2; ++kc) {
            const int off = (nt * 16 + l15) * 72 + kc * 32 + lk * 8;
            Br[nt][kc] = *(const short8v*)(lds + off);
            Bi[nt][kc] = *(const short8v*)(lds + 2304 + off);
        }
    }

    #pragma unroll
    for (int mt = 0; mt < 2; ++mt) {
        const int lt = wv * 2 + mt;       // local 16-row tile 0..7
        const int HT = hh * 8 + lt;       // global tile 0..15
        f32x4 zr[2] = {f32x4{0,0,0,0}, f32x4{0,0,0,0}};
        f32x4 zi[2] = {f32x4{0,0,0,0}, f32x4{0,0,0,0}};
        #pragma unroll
        for (int kc = 0; kc < 2; ++kc) {
            const int abase = ((HT * 2 + kc) * 64 + lane) * 8;
            const short8v C = *(const short8v*)(C4 + abase);
            const short8v S = *(const short8v*)(S4 + abase);
            const short8v N = *(const short8v*)(N4 + abase);
            #pragma unroll
            for (int nt = 0; nt < 2; ++nt) {
                zr[nt] = __builtin_amdgcn_mfma_f32_16x16x32_bf16(C, Br[nt][kc], zr[nt], 0, 0, 0);
                zr[nt] = __builtin_amdgcn_mfma_f32_16x16x32_bf16(N, Bi[nt][kc], zr[nt], 0, 0, 0);
                zi[nt] = __builtin_amdgcn_mfma_f32_16x16x32_bf16(S, Br[nt][kc], zi[nt], 0, 0, 0);
                zi[nt] = __builtin_amdgcn_mfma_f32_16x16x32_bf16(C, Bi[nt][kc], zi[nt], 0, 0, 0);
            }
        }
        #pragma unroll
        for (int nt = 0; nt < 2; ++nt) {
            const int kx = nt * 16 + l15;
            #pragma unroll
            for (int r = 0; r < 4; ++r) {
                const int hl = lt * 16 + lk * 4 + r;
                const u32 pk = (u32)bf16_rtn(zr[nt][r]) | ((u32)bf16_rtn(zi[nt][r]) << 16);
                *(u32*)(lds + 4608 + hl * 72 + 2 * kx) = pk;
            }
        }
    }
    __syncthreads();

    // Phase 5 (transposed): A = W5 frag (row=w), B = Z^T frag (col=h).
    const u16* __restrict__ W5 = tw2 + 49152;
    float* __restrict__ op = out + (size_t)blockIdx.x * (NH * NW) + (size_t)hh * 128 * NW;

    short8v Bz[2][2];                     // Z^T frags, fixed per wave
    #pragma unroll
    for (int mt = 0; mt < 2; ++mt) {
        const int lt = wv * 2 + mt;
        #pragma unroll
        for (int kc = 0; kc < 2; ++kc)
            Bz[mt][kc] = *(const short8v*)(lds + 4608 + (lt * 16 + l15) * 72 + kc * 32 + lk * 8);
    }

    for (int wt = 0; wt < 16; ++wt) {
        const short8v A0 = *(const short8v*)(W5 + ((wt * 2 + 0) * 64 + lane) * 8);
        const short8v A1 = *(const short8v*)(W5 + ((wt * 2 + 1) * 64 + lane) * 8);
        #pragma unroll
        for (int mt = 0; mt < 2; ++mt) {
            const int lt = wv * 2 + mt;
            f32x4 acc = {0, 0, 0, 0};
            acc = __builtin_amdgcn_mfma_f32_16x16x32_bf16(A0, Bz[mt][0], acc, 0, 0, 0);
            acc = __builtin_amdgcn_mfma_f32_16x16x32_bf16(A1, Bz[mt][1], acc, 0, 0, 0);
            // D[w = wt*16+lk*4+r][h = lt*16+l15] -> 4 consecutive w: one dwordx4
            *(float4*)&op[(lt * 16 + l15) * 256 + wt * 16 + lk * 4] =
                make_float4(acc[0], acc[1], acc[2], acc[3]);
        }
    }
}

extern "C" void kernel_launch(void* const* d_in, const int* in_sizes, int n_in,
                              void* d_out, int out_size, void* d_ws, size_t ws_size,
                              hipStream_t stream) {
    const float* x  = (const float*)d_in[0];
    const int* q1   = (const int*)d_in[1];
    const int* q2   = (const int*)d_in[2];
    const float* w1s = (const float*)d_in[3];
    const float* w1m = (const float*)d_in[4];
    const float* w2s = (const float*)d_in[5];
    const float* w2m = (const float*)d_in[6];
    float* out = (float*)d_out;

    float2* xft  = (float2*)d_ws;                           // [0, 16 MiB)
    float2* oft0 = xft + (size_t)NB * NCIN * NM * NKX;      // [16, 32 MiB)
    float2* oft1 = oft0 + (size_t)NB * NCOUT * NM * NKX;    // [32, 48 MiB)
    u16* tw  = (u16*)((char*)d_ws + (size_t)48 * 1024 * 1024);  // 256 KiB
    u16* tw2 = tw + 131072;                                      // 128 KiB

    init_tw<<<128, 256, 0, stream>>>(tw);
    init_tw2<<<128, 256, 0, stream>>>(tw2);
    fwd_mfma<<<NB * NCIN, 256, 0, stream>>>(x, tw, xft);
    mode_v4<<<dim3(NM, 4, 8), 256, 0, stream>>>(xft, q1, q2, w1s, w1m, w2s, w2m, oft0, oft1);
    inv_mfma2<<<dim3(NB * NCOUT, 2), 256, 0, stream>>>(oft0, oft1, tw2, out);
}

// Round 7
// 242.778 us; speedup vs baseline: 1.0393x; 1.0393x over previous
//
#include <hip/hip_runtime.h>
#include <math.h>

#define NB 16
#define NCIN 64
#define NCOUT 64
#define NH 256
#define NW 256
#define NM 64          // 2*M1 row modes
#define NKX 32         // M2 retained columns
#define INV256 (1.0f/256.0f)

typedef __attribute__((ext_vector_type(8))) short short8v;
typedef __attribute__((ext_vector_type(4))) float f32x4;
typedef unsigned short u16;
typedef unsigned int u32;

__device__ __forceinline__ void bf16_split(float v, u16& hi, u16& lo) {
    u32 b = __float_as_uint(v);
    u32 hib = b & 0xffff0000u;
    float lof = v - __uint_as_float(hib);
    hi = (u16)(hib >> 16);
    lo = (u16)(__float_as_uint(lof) >> 16);
}

__device__ __forceinline__ u16 bf16_rtn(float v) {
    u32 b = __float_as_uint(v);
    u32 r = b + 0x7fffu + ((b >> 16) & 1u);
    return (u16)(r >> 16);
}

// ---------------- fwd twiddle tables (dedicated region @ ws+48MiB) ----------
//  T1h @ 0      T1l @ 16384   : [kc 8][nt 4][lane 64][e 8]  (phase-1 B frags)
//  C2h @ 32768  C2l @ 49152   : [mt 4][kc 8][lane 64][e 8]  (phase-2 A frags)
//  S2h @ 65536  S2l @ 81920
//  Snh @ 98304  Snl @ 114688
__global__ __launch_bounds__(256) void init_tw(u16* __restrict__ tw) {
    const int tid = blockIdx.x * 256 + threadIdx.x;   // 0..32767
    const float TWO_PI = 6.28318530717958647692f;
    if (tid < 16384) {
        const int e = tid & 7, lane = (tid >> 3) & 63;
        const int nt = (tid >> 9) & 3, kc = tid >> 11;
        const int w = kc * 32 + (lane >> 4) * 8 + e;
        const int n = nt * 16 + (lane & 15);
        const int kx = n >> 1, p = n & 1;
        const float ang = TWO_PI * (float)((kx * w) & 255) * INV256;
        const float v = p ? -sinf(ang) : cosf(ang);
        u16 hi, lo; bf16_split(v, hi, lo);
        tw[tid] = hi; tw[16384 + tid] = lo;
    } else {
        const int u = tid - 16384;
        const int e = u & 7, lane = (u >> 3) & 63;
        const int kc = (u >> 9) & 7, mt = u >> 12;
        const int m = mt * 16 + (lane & 15);
        const int h = kc * 32 + (lane >> 4) * 8 + e;
        const int ky = (m < 32) ? m : (192 + m);
        const float ang = TWO_PI * (float)((ky * h) & 255) * INV256;
        const float c = cosf(ang), s = sinf(ang);
        u16 hi, lo;
        bf16_split(c,  hi, lo); tw[32768 + u] = hi; tw[49152 + u]  = lo;
        bf16_split(s,  hi, lo); tw[65536 + u] = hi; tw[81920 + u]  = lo;
        bf16_split(-s, hi, lo); tw[98304 + u] = hi; tw[114688 + u] = lo;
    }
}

// ---------------- inv twiddle tables (own region, after tw) -----------------
//  C4 @ 0      S4 @ 16384    N4 @ 32768 : [HT 16][kc 2][lane 64][e 8]
//  W5 @ 49152                           : [wt 16][kc 2][lane 64][e 8]
//  W5 serves as A-frag (row=w=lane&15) AND B-frag (col=w) — same mapping.
//  k-order interleaved: kk = 2*kx + c; c=0 -> wt*cos/256, c=1 -> -wt*sin/256
__global__ __launch_bounds__(256) void init_tw2(u16* __restrict__ tw2) {
    const int tid = blockIdx.x * 256 + threadIdx.x;   // 0..32767
    const float TWO_PI = 6.28318530717958647692f;
    if (tid < 16384) {
        const int e = tid & 7, lane = (tid >> 3) & 63;
        const int kc = (tid >> 9) & 1, HT = tid >> 10;
        const int h = HT * 16 + (lane & 15);
        const int m = kc * 32 + ((lane >> 4) << 3) + e;
        const int ky = (m < 32) ? m : (192 + m);
        const float ang = TWO_PI * (float)((ky * h) & 255) * INV256;
        tw2[tid]         = bf16_rtn(cosf(ang));
        tw2[16384 + tid] = bf16_rtn(sinf(ang));
        tw2[32768 + tid] = bf16_rtn(-sinf(ang));
    } else {
        const int u = tid - 16384;
        const int e = u & 7, lane = (u >> 3) & 63;
        const int kc = (u >> 9) & 1, nt = u >> 10;
        const int w = nt * 16 + (lane & 15);
        const int kk = kc * 32 + ((lane >> 4) << 3) + e;
        const int kx = kk >> 1, c = kk & 1;
        const float wt = (kx == 0) ? 1.f : 2.f;
        const float ang = TWO_PI * (float)((kx * w) & 255) * INV256;
        const float v = c ? (-wt * sinf(ang) * INV256) : (wt * cosf(ang) * INV256);
        tw2[49152 + u] = bf16_rtn(v);
    }
}

// ---------------- Kernel 1: forward partial rfft2 via MFMA ----------------
__global__ __launch_bounds__(256) void fwd_mfma(const float* __restrict__ x,
                                                const u16* __restrict__ tw,
                                                float2* __restrict__ xft) {
    __shared__ u16 planes[4 * 32 * 264];   // 67584 B
    const int t = threadIdx.x;
    const int lane = t & 63;
    const int wv = t >> 6;
    const int l15 = lane & 15;
    const int lk = lane >> 4;
    const float* __restrict__ xb = x + (size_t)blockIdx.x * (NH * NW);

    const u16* __restrict__ T1h = tw;
    const u16* __restrict__ T1l = tw + 16384;

    for (int mt = 0; mt < 4; ++mt) {
        const int hbase = wv * 64 + mt * 16;
        f32x4 acc[4] = {f32x4{0,0,0,0}, f32x4{0,0,0,0}, f32x4{0,0,0,0}, f32x4{0,0,0,0}};
        for (int kc = 0; kc < 8; ++kc) {
            const float* xr = xb + (size_t)(hbase + l15) * NW + kc * 32 + lk * 8;
            const float4 xa = *(const float4*)xr;
            const float4 xc = *(const float4*)(xr + 4);
            const float v[8] = {xa.x, xa.y, xa.z, xa.w, xc.x, xc.y, xc.z, xc.w};
            short8v Ah, Al;
            #pragma unroll
            for (int e = 0; e < 8; ++e) {
                u16 hi, lo; bf16_split(v[e], hi, lo);
                Ah[e] = (short)hi; Al[e] = (short)lo;
            }
            const int tbase = (kc * 4) * 512 + lane * 8;
            #pragma unroll
            for (int nt = 0; nt < 4; ++nt) {
                const short8v Bh = *(const short8v*)(T1h + tbase + nt * 512);
                const short8v Bl = *(const short8v*)(T1l + tbase + nt * 512);
                acc[nt] = __builtin_amdgcn_mfma_f32_16x16x32_bf16(Ah, Bh, acc[nt], 0, 0, 0);
                acc[nt] = __builtin_amdgcn_mfma_f32_16x16x32_bf16(Ah, Bl, acc[nt], 0, 0, 0);
                acc[nt] = __builtin_amdgcn_mfma_f32_16x16x32_bf16(Al, Bh, acc[nt], 0, 0, 0);
            }
        }
        #pragma unroll
        for (int nt = 0; nt < 4; ++nt) {
            const int n = nt * 16 + l15;
            const int kx = n >> 1, p = n & 1;
            #pragma unroll
            for (int r = 0; r < 4; ++r) {
                const int h = hbase + lk * 4 + r;
                u16 hi, lo; bf16_split(acc[nt][r], hi, lo);
                planes[(2 * p) * 8448 + kx * 264 + h] = hi;
                planes[(2 * p + 1) * 8448 + kx * 264 + h] = lo;
            }
        }
    }
    __syncthreads();

    const u16* __restrict__ C2h = tw + 32768;
    const u16* __restrict__ C2l = tw + 49152;
    const u16* __restrict__ S2h = tw + 65536;
    const u16* __restrict__ S2l = tw + 81920;
    const u16* __restrict__ Snh = tw + 98304;
    const u16* __restrict__ Snl = tw + 114688;

    f32x4 zre[2] = {f32x4{0,0,0,0}, f32x4{0,0,0,0}};
    f32x4 zim[2] = {f32x4{0,0,0,0}, f32x4{0,0,0,0}};
    for (int kc = 0; kc < 8; ++kc) {
        const int abase = (wv * 8 + kc) * 512 + lane * 8;
        const short8v Ch = *(const short8v*)(C2h + abase);
        const short8v Cl = *(const short8v*)(C2l + abase);
        const short8v Sh = *(const short8v*)(S2h + abase);
        const short8v Sl = *(const short8v*)(S2l + abase);
        const short8v Nh = *(const short8v*)(Snh + abase);
        const short8v Nl = *(const short8v*)(Snl + abase);
        #pragma unroll
        for (int nt = 0; nt < 2; ++nt) {
            const int kx = nt * 16 + l15;
            const int off = kx * 264 + kc * 32 + lk * 8;
            const short8v Yrh = *(const short8v*)(planes + off);
            const short8v Yrl = *(const short8v*)(planes + 8448 + off);
            const short8v Yih = *(const short8v*)(planes + 16896 + off);
            const short8v Yil = *(const short8v*)(planes + 25344 + off);
            zre[nt] = __builtin_amdgcn_mfma_f32_16x16x32_bf16(Ch, Yrh, zre[nt], 0, 0, 0);
            zre[nt] = __builtin_amdgcn_mfma_f32_16x16x32_bf16(Ch, Yrl, zre[nt], 0, 0, 0);
            zre[nt] = __builtin_amdgcn_mfma_f32_16x16x32_bf16(Cl, Yrh, zre[nt], 0, 0, 0);
            zre[nt] = __builtin_amdgcn_mfma_f32_16x16x32_bf16(Sh, Yih, zre[nt], 0, 0, 0);
            zre[nt] = __builtin_amdgcn_mfma_f32_16x16x32_bf16(Sh, Yil, zre[nt], 0, 0, 0);
            zre[nt] = __builtin_amdgcn_mfma_f32_16x16x32_bf16(Sl, Yih, zre[nt], 0, 0, 0);
            zim[nt] = __builtin_amdgcn_mfma_f32_16x16x32_bf16(Ch, Yih, zim[nt], 0, 0, 0);
            zim[nt] = __builtin_amdgcn_mfma_f32_16x16x32_bf16(Ch, Yil, zim[nt], 0, 0, 0);
            zim[nt] = __builtin_amdgcn_mfma_f32_16x16x32_bf16(Cl, Yih, zim[nt], 0, 0, 0);
            zim[nt] = __builtin_amdgcn_mfma_f32_16x16x32_bf16(Nh, Yrh, zim[nt], 0, 0, 0);
            zim[nt] = __builtin_amdgcn_mfma_f32_16x16x32_bf16(Nh, Yrl, zim[nt], 0, 0, 0);
            zim[nt] = __builtin_amdgcn_mfma_f32_16x16x32_bf16(Nl, Yrh, zim[nt], 0, 0, 0);
        }
    }
    float2* __restrict__ op = xft + (size_t)blockIdx.x * (NM * NKX);
    #pragma unroll
    for (int nt = 0; nt < 2; ++nt) {
        const int kx = nt * 16 + l15;
        #pragma unroll
        for (int r = 0; r < 4; ++r) {
            const int m = wv * 16 + lk * 4 + r;
            op[m * NKX + kx] = make_float2(zre[nt][r] * INV256, zim[nt][r] * INV256);
        }
    }
}

// ---------------- Kernel 2: per-mode channel contraction (v3) ----------------
// grid = (m=64, og=4, kh=4), 256 threads. Depth-2 register prefetch:
// at iter i: compute(i from LDS) -> write reg(i+1) -> barrier -> issue load(i+3).
__global__ __launch_bounds__(256) void mode_v3(const float2* __restrict__ xft,
                                               const int* __restrict__ q1,
                                               const int* __restrict__ q2,
                                               const float* __restrict__ w1s,
                                               const float* __restrict__ w1m,
                                               const float* __restrict__ w2s,
                                               const float* __restrict__ w2m,
                                               float2* __restrict__ oft) {
    __shared__ float2 xs[2][16][8];     // [buf][b][kx] — reads are 16-way broadcast
    __shared__ float2 ws[2][16][9];     // [buf][o][kx] pad-9 -> conflict-free reads
    const int m  = blockIdx.x;          // 0..63
    const int og = blockIdx.y;          // 0..3
    const int kh = blockIdx.z;          // 0..3
    const int t = threadIdx.x;
    const int b = t >> 4, o = t & 15;
    const int mm = (m < 32) ? m : (m - 32);
    const int2* __restrict__ qp = (const int2*)((m < 32) ? q1 : q2);
    const float scale = (m < 32) ? w1s[0] : w2s[0];
    const float wmin  = (m < 32) ? w1m[0] : w2m[0];

    const bool isx = t < 128;           // wave-uniform
    const int r8 = (t & 127) >> 3;      // 0..15 (row: b for x-loaders, o for w-loaders)
    const int k8 = t & 7;               // 0..7  (kx within this kh group)

    const float2* __restrict__ xsrc = xft + (size_t)(r8 * 64) * (NM * NKX)
                                          + m * NKX + kh * 8 + k8;          // += 2048/i
    const int2* __restrict__ wsrc = qp + (size_t)(og * 16 + r8) * 1024
                                       + mm * 32 + kh * 8 + k8;             // += 65536/i

    // prologue: data0 -> LDS[0]; pb <- data1; pa <- data2
    float2 pxa, pxb; int2 pwa, pwb;
    if (isx) {
        const float2 p0 = xsrc[0];
        xs[0][r8][k8] = p0;
        pxb = xsrc[(size_t)1 * (NM * NKX)];
        pxa = xsrc[(size_t)2 * (NM * NKX)];
    } else {
        const int2 p0 = wsrc[0];
        ws[0][r8][k8] = make_float2(((float)p0.x + 127.0f) * scale + wmin,
                                    ((float)p0.y + 127.0f) * scale + wmin);
        pwb = wsrc[(size_t)1 * 65536];
        pwa = wsrc[(size_t)2 * 65536];
    }
    __syncthreads();

    float accr[8], acci[8];
    #pragma unroll
    for (int k = 0; k < 8; ++k) { accr[k] = 0.f; acci[k] = 0.f; }

    #pragma unroll 1
    for (int j = 0; j < 32; ++j) {
        const int i0 = 2 * j;           // even iter: compute LDS[0], write pb->LDS[1]
        #pragma unroll
        for (int k = 0; k < 8; ++k) {
            const float2 xv = xs[0][b][k];
            const float2 wv = ws[0][o][k];
            accr[k] += xv.x * wv.x - xv.y * wv.y;
            acci[k] += xv.x * wv.y + xv.y * wv.x;
        }
        {   // i0 <= 62 always: write data(i0+1)
            if (isx) xs[1][r8][k8] = pxb;
            else     ws[1][r8][k8] = make_float2(((float)pwb.x + 127.0f) * scale + wmin,
                                                 ((float)pwb.y + 127.0f) * scale + wmin);
            __syncthreads();
            if (i0 + 3 < 64) {
                if (isx) pxb = xsrc[(size_t)(i0 + 3) * (NM * NKX)];
                else     pwb = wsrc[(size_t)(i0 + 3) * 65536];
            }
        }
        const int i1 = 2 * j + 1;       // odd iter: compute LDS[1], write pa->LDS[0]
        #pragma unroll
        for (int k = 0; k < 8; ++k) {
            const float2 xv = xs[1][b][k];
            const float2 wv = ws[1][o][k];
            accr[k] += xv.x * wv.x - xv.y * wv.y;
            acci[k] += xv.x * wv.y + xv.y * wv.x;
        }
        if (i1 < 63) {                  // write data(i1+1)
            if (isx) xs[0][r8][k8] = pxa;
            else     ws[0][r8][k8] = make_float2(((float)pwa.x + 127.0f) * scale + wmin,
                                                 ((float)pwa.y + 127.0f) * scale + wmin);
            __syncthreads();
            if (i1 + 3 < 64) {
                if (isx) pxa = xsrc[(size_t)(i1 + 3) * (NM * NKX)];
                else     pwa = wsrc[(size_t)(i1 + 3) * 65536];
            }
        }
    }

    float2* __restrict__ op = oft + ((size_t)(b * 64 + og * 16 + o) * NM + m) * NKX + kh * 8;
    #pragma unroll
    for (int k = 0; k < 8; ++k) op[k] = make_float2(accr[k], acci[k]);
}

// ---------------- Kernel 3: inverse partial irfft2 via MFMA (v3) ------------
// grid = (B*COUT, 2), 256 threads. Block handles 128 h rows. SINGLE oft input.
// Phase 4: Z[128h][32kx](re,im) = twiddle[h][m] x O[m][kx]   (K=64)
// Phase 5 TRANSPOSED: D[w][h] = W5^T[w][kk] x Z^T[kk][h] -> dwordx4 stores.
// LDS (ushort): OrP @0 [32kx][72], OiP @2304, Zp @4608 [128hl][72]
__global__ __launch_bounds__(256) void inv_mfma3(const float2* __restrict__ oft,
                                                 const u16* __restrict__ tw2,
                                                 float* __restrict__ out) {
    __shared__ u16 lds[13824];   // 27648 B
    const int t = threadIdx.x;
    const int lane = t & 63;
    const int wv = t >> 6;
    const int l15 = lane & 15;
    const int lk = lane >> 4;
    const int hh = blockIdx.y;   // 0/1: h half

    const float4* __restrict__ p0 = (const float4*)(oft + (size_t)blockIdx.x * (NM * NKX));
    #pragma unroll
    for (int rep = 0; rep < 4; ++rep) {
        const int idx4 = rep * 256 + t;
        const float4 a = p0[idx4];
        const int e0 = idx4 * 2;
        const int m = e0 >> 5, kx = e0 & 31;   // kx even, kx+1 valid
        lds[kx * 72 + m]              = bf16_rtn(a.x);
        lds[2304 + kx * 72 + m]       = bf16_rtn(a.y);
        lds[(kx + 1) * 72 + m]        = bf16_rtn(a.z);
        lds[2304 + (kx + 1) * 72 + m] = bf16_rtn(a.w);
    }
    __syncthreads();

    const u16* __restrict__ C4 = tw2;
    const u16* __restrict__ S4 = tw2 + 16384;
    const u16* __restrict__ N4 = tw2 + 32768;

    short8v Br[2][2], Bi[2][2];
    #pragma unroll
    for (int nt = 0; nt < 2; ++nt) {
        #pragma unroll
        for (int kc = 0; kc < 2; ++kc) {
            const int off = (nt * 16 + l15) * 72 + kc * 32 + lk * 8;
            Br[nt][kc] = *(const short8v*)(lds + off);
            Bi[nt][kc] = *(const short8v*)(lds + 2304 + off);
        }
    }

    #pragma unroll
    for (int mt = 0; mt < 2; ++mt) {
        const int lt = wv * 2 + mt;       // local 16-row tile 0..7
        const int HT = hh * 8 + lt;       // global tile 0..15
        f32x4 zr[2] = {f32x4{0,0,0,0}, f32x4{0,0,0,0}};
        f32x4 zi[2] = {f32x4{0,0,0,0}, f32x4{0,0,0,0}};
        #pragma unroll
        for (int kc = 0; kc < 2; ++kc) {
            const int abase = ((HT * 2 + kc) * 64 + lane) * 8;
            const short8v C = *(const short8v*)(C4 + abase);
            const short8v S = *(const short8v*)(S4 + abase);
            const short8v N = *(const short8v*)(N4 + abase);
            #pragma unroll
            for (int nt = 0; nt < 2; ++nt) {
                zr[nt] = __builtin_amdgcn_mfma_f32_16x16x32_bf16(C, Br[nt][kc], zr[nt], 0, 0, 0);
                zr[nt] = __builtin_amdgcn_mfma_f32_16x16x32_bf16(N, Bi[nt][kc], zr[nt], 0, 0, 0);
                zi[nt] = __builtin_amdgcn_mfma_f32_16x16x32_bf16(S, Br[nt][kc], zi[nt], 0, 0, 0);
                zi[nt] = __builtin_amdgcn_mfma_f32_16x16x32_bf16(C, Bi[nt][kc], zi[nt], 0, 0, 0);
            }
        }
        #pragma unroll
        for (int nt = 0; nt < 2; ++nt) {
            const int kx = nt * 16 + l15;
            #pragma unroll
            for (int r = 0; r < 4; ++r) {
                const int hl = lt * 16 + lk * 4 + r;
                const u32 pk = (u32)bf16_rtn(zr[nt][r]) | ((u32)bf16_rtn(zi[nt][r]) << 16);
                *(u32*)(lds + 4608 + hl * 72 + 2 * kx) = pk;
            }
        }
    }
    __syncthreads();

    // Phase 5 (transposed): A = W5 frag (row=w), B = Z^T frag (col=h).
    const u16* __restrict__ W5 = tw2 + 49152;
    float* __restrict__ op = out + (size_t)blockIdx.x * (NH * NW) + (size_t)hh * 128 * NW;

    short8v Bz[2][2];                     // Z^T frags, fixed per wave
    #pragma unroll
    for (int mt = 0; mt < 2; ++mt) {
        const int lt = wv * 2 + mt;
        #pragma unroll
        for (int kc = 0; kc < 2; ++kc)
            Bz[mt][kc] = *(const short8v*)(lds + 4608 + (lt * 16 + l15) * 72 + kc * 32 + lk * 8);
    }

    for (int wt = 0; wt < 16; ++wt) {
        const short8v A0 = *(const short8v*)(W5 + ((wt * 2 + 0) * 64 + lane) * 8);
        const short8v A1 = *(const short8v*)(W5 + ((wt * 2 + 1) * 64 + lane) * 8);
        #pragma unroll
        for (int mt = 0; mt < 2; ++mt) {
            const int lt = wv * 2 + mt;
            f32x4 acc = {0, 0, 0, 0};
            acc = __builtin_amdgcn_mfma_f32_16x16x32_bf16(A0, Bz[mt][0], acc, 0, 0, 0);
            acc = __builtin_amdgcn_mfma_f32_16x16x32_bf16(A1, Bz[mt][1], acc, 0, 0, 0);
            // D[w = wt*16+lk*4+r][h = lt*16+l15] -> 4 consecutive w: one dwordx4
            *(float4*)&op[(lt * 16 + l15) * 256 + wt * 16 + lk * 4] =
                make_float4(acc[0], acc[1], acc[2], acc[3]);
        }
    }
}

extern "C" void kernel_launch(void* const* d_in, const int* in_sizes, int n_in,
                              void* d_out, int out_size, void* d_ws, size_t ws_size,
                              hipStream_t stream) {
    const float* x  = (const float*)d_in[0];
    const int* q1   = (const int*)d_in[1];
    const int* q2   = (const int*)d_in[2];
    const float* w1s = (const float*)d_in[3];
    const float* w1m = (const float*)d_in[4];
    const float* w2s = (const float*)d_in[5];
    const float* w2m = (const float*)d_in[6];
    float* out = (float*)d_out;

    float2* xft = (float2*)d_ws;                          // [0, 16 MiB)
    float2* oft = xft + (size_t)NB * NCIN * NM * NKX;     // [16, 32 MiB)
    u16* tw  = (u16*)((char*)d_ws + (size_t)48 * 1024 * 1024);  // 256 KiB
    u16* tw2 = tw + 131072;                                      // 128 KiB

    init_tw<<<128, 256, 0, stream>>>(tw);
    init_tw2<<<128, 256, 0, stream>>>(tw2);
    fwd_mfma<<<NB * NCIN, 256, 0, stream>>>(x, tw, xft);
    mode_v3<<<dim3(NM, 4, 4), 256, 0, stream>>>(xft, q1, q2, w1s, w1m, w2s, w2m, oft);
    inv_mfma3<<<dim3(NB * NCOUT, 2), 256, 0, stream>>>(oft, tw2, out);
}

// Round 8
// 220.700 us; speedup vs baseline: 1.1433x; 1.1000x over previous
//
#include <hip/hip_runtime.h>
#include <math.h>

#define NB 16
#define NCIN 64
#define NCOUT 64
#define NH 256
#define NW 256
#define NM 64          // 2*M1 row modes
#define NKX 32         // M2 retained columns
#define INV256 (1.0f/256.0f)

typedef __attribute__((ext_vector_type(8))) short short8v;
typedef __attribute__((ext_vector_type(4))) float f32x4;
typedef unsigned short u16;
typedef unsigned int u32;

__device__ __forceinline__ void bf16_split(float v, u16& hi, u16& lo) {
    u32 b = __float_as_uint(v);
    u32 hib = b & 0xffff0000u;
    float lof = v - __uint_as_float(hib);
    hi = (u16)(hib >> 16);
    lo = (u16)(__float_as_uint(lof) >> 16);
}

__device__ __forceinline__ u16 bf16_rtn(float v) {
    u32 b = __float_as_uint(v);
    u32 r = b + 0x7fffu + ((b >> 16) & 1u);
    return (u16)(r >> 16);
}

// ---------------- fwd twiddle tables (dedicated region @ ws+48MiB) ----------
__global__ __launch_bounds__(256) void init_tw(u16* __restrict__ tw) {
    const int tid = blockIdx.x * 256 + threadIdx.x;   // 0..32767
    const float TWO_PI = 6.28318530717958647692f;
    if (tid < 16384) {
        const int e = tid & 7, lane = (tid >> 3) & 63;
        const int nt = (tid >> 9) & 3, kc = tid >> 11;
        const int w = kc * 32 + (lane >> 4) * 8 + e;
        const int n = nt * 16 + (lane & 15);
        const int kx = n >> 1, p = n & 1;
        const float ang = TWO_PI * (float)((kx * w) & 255) * INV256;
        const float v = p ? -sinf(ang) : cosf(ang);
        u16 hi, lo; bf16_split(v, hi, lo);
        tw[tid] = hi; tw[16384 + tid] = lo;
    } else {
        const int u = tid - 16384;
        const int e = u & 7, lane = (u >> 3) & 63;
        const int kc = (u >> 9) & 7, mt = u >> 12;
        const int m = mt * 16 + (lane & 15);
        const int h = kc * 32 + (lane >> 4) * 8 + e;
        const int ky = (m < 32) ? m : (192 + m);
        const float ang = TWO_PI * (float)((ky * h) & 255) * INV256;
        const float c = cosf(ang), s = sinf(ang);
        u16 hi, lo;
        bf16_split(c,  hi, lo); tw[32768 + u] = hi; tw[49152 + u]  = lo;
        bf16_split(s,  hi, lo); tw[65536 + u] = hi; tw[81920 + u]  = lo;
        bf16_split(-s, hi, lo); tw[98304 + u] = hi; tw[114688 + u] = lo;
    }
}

// ---------------- inv twiddle tables ----------------------------------------
__global__ __launch_bounds__(256) void init_tw2(u16* __restrict__ tw2) {
    const int tid = blockIdx.x * 256 + threadIdx.x;   // 0..32767
    const float TWO_PI = 6.28318530717958647692f;
    if (tid < 16384) {
        const int e = tid & 7, lane = (tid >> 3) & 63;
        const int kc = (tid >> 9) & 1, HT = tid >> 10;
        const int h = HT * 16 + (lane & 15);
        const int m = kc * 32 + ((lane >> 4) << 3) + e;
        const int ky = (m < 32) ? m : (192 + m);
        const float ang = TWO_PI * (float)((ky * h) & 255) * INV256;
        tw2[tid]         = bf16_rtn(cosf(ang));
        tw2[16384 + tid] = bf16_rtn(sinf(ang));
        tw2[32768 + tid] = bf16_rtn(-sinf(ang));
    } else {
        const int u = tid - 16384;
        const int e = u & 7, lane = (u >> 3) & 63;
        const int kc = (u >> 9) & 1, nt = u >> 10;
        const int w = nt * 16 + (lane & 15);
        const int kk = kc * 32 + ((lane >> 4) << 3) + e;
        const int kx = kk >> 1, c = kk & 1;
        const float wt = (kx == 0) ? 1.f : 2.f;
        const float ang = TWO_PI * (float)((kx * w) & 255) * INV256;
        const float v = c ? (-wt * sinf(ang) * INV256) : (wt * cosf(ang) * INV256);
        tw2[49152 + u] = bf16_rtn(v);
    }
}

// ---------------- Kernel 1: forward partial rfft2 via MFMA ----------------
__global__ __launch_bounds__(256) void fwd_mfma(const float* __restrict__ x,
                                                const u16* __restrict__ tw,
                                                float2* __restrict__ xft) {
    __shared__ u16 planes[4 * 32 * 264];   // 67584 B
    const int t = threadIdx.x;
    const int lane = t & 63;
    const int wv = t >> 6;
    const int l15 = lane & 15;
    const int lk = lane >> 4;
    const float* __restrict__ xb = x + (size_t)blockIdx.x * (NH * NW);

    const u16* __restrict__ T1h = tw;
    const u16* __restrict__ T1l = tw + 16384;

    for (int mt = 0; mt < 4; ++mt) {
        const int hbase = wv * 64 + mt * 16;
        f32x4 acc[4] = {f32x4{0,0,0,0}, f32x4{0,0,0,0}, f32x4{0,0,0,0}, f32x4{0,0,0,0}};
        for (int kc = 0; kc < 8; ++kc) {
            const float* xr = xb + (size_t)(hbase + l15) * NW + kc * 32 + lk * 8;
            const float4 xa = *(const float4*)xr;
            const float4 xc = *(const float4*)(xr + 4);
            const float v[8] = {xa.x, xa.y, xa.z, xa.w, xc.x, xc.y, xc.z, xc.w};
            short8v Ah, Al;
            #pragma unroll
            for (int e = 0; e < 8; ++e) {
                u16 hi, lo; bf16_split(v[e], hi, lo);
                Ah[e] = (short)hi; Al[e] = (short)lo;
            }
            const int tbase = (kc * 4) * 512 + lane * 8;
            #pragma unroll
            for (int nt = 0; nt < 4; ++nt) {
                const short8v Bh = *(const short8v*)(T1h + tbase + nt * 512);
                const short8v Bl = *(const short8v*)(T1l + tbase + nt * 512);
                acc[nt] = __builtin_amdgcn_mfma_f32_16x16x32_bf16(Ah, Bh, acc[nt], 0, 0, 0);
                acc[nt] = __builtin_amdgcn_mfma_f32_16x16x32_bf16(Ah, Bl, acc[nt], 0, 0, 0);
                acc[nt] = __builtin_amdgcn_mfma_f32_16x16x32_bf16(Al, Bh, acc[nt], 0, 0, 0);
            }
        }
        #pragma unroll
        for (int nt = 0; nt < 4; ++nt) {
            const int n = nt * 16 + l15;
            const int kx = n >> 1, p = n & 1;
            #pragma unroll
            for (int r = 0; r < 4; ++r) {
                const int h = hbase + lk * 4 + r;
                u16 hi, lo; bf16_split(acc[nt][r], hi, lo);
                planes[(2 * p) * 8448 + kx * 264 + h] = hi;
                planes[(2 * p + 1) * 8448 + kx * 264 + h] = lo;
            }
        }
    }
    __syncthreads();

    const u16* __restrict__ C2h = tw + 32768;
    const u16* __restrict__ C2l = tw + 49152;
    const u16* __restrict__ S2h = tw + 65536;
    const u16* __restrict__ S2l = tw + 81920;
    const u16* __restrict__ Snh = tw + 98304;
    const u16* __restrict__ Snl = tw + 114688;

    f32x4 zre[2] = {f32x4{0,0,0,0}, f32x4{0,0,0,0}};
    f32x4 zim[2] = {f32x4{0,0,0,0}, f32x4{0,0,0,0}};
    for (int kc = 0; kc < 8; ++kc) {
        const int abase = (wv * 8 + kc) * 512 + lane * 8;
        const short8v Ch = *(const short8v*)(C2h + abase);
        const short8v Cl = *(const short8v*)(C2l + abase);
        const short8v Sh = *(const short8v*)(S2h + abase);
        const short8v Sl = *(const short8v*)(S2l + abase);
        const short8v Nh = *(const short8v*)(Snh + abase);
        const short8v Nl = *(const short8v*)(Snl + abase);
        #pragma unroll
        for (int nt = 0; nt < 2; ++nt) {
            const int kx = nt * 16 + l15;
            const int off = kx * 264 + kc * 32 + lk * 8;
            const short8v Yrh = *(const short8v*)(planes + off);
            const short8v Yrl = *(const short8v*)(planes + 8448 + off);
            const short8v Yih = *(const short8v*)(planes + 16896 + off);
            const short8v Yil = *(const short8v*)(planes + 25344 + off);
            zre[nt] = __builtin_amdgcn_mfma_f32_16x16x32_bf16(Ch, Yrh, zre[nt], 0, 0, 0);
            zre[nt] = __builtin_amdgcn_mfma_f32_16x16x32_bf16(Ch, Yrl, zre[nt], 0, 0, 0);
            zre[nt] = __builtin_amdgcn_mfma_f32_16x16x32_bf16(Cl, Yrh, zre[nt], 0, 0, 0);
            zre[nt] = __builtin_amdgcn_mfma_f32_16x16x32_bf16(Sh, Yih, zre[nt], 0, 0, 0);
            zre[nt] = __builtin_amdgcn_mfma_f32_16x16x32_bf16(Sh, Yil, zre[nt], 0, 0, 0);
            zre[nt] = __builtin_amdgcn_mfma_f32_16x16x32_bf16(Sl, Yih, zre[nt], 0, 0, 0);
            zim[nt] = __builtin_amdgcn_mfma_f32_16x16x32_bf16(Ch, Yih, zim[nt], 0, 0, 0);
            zim[nt] = __builtin_amdgcn_mfma_f32_16x16x32_bf16(Ch, Yil, zim[nt], 0, 0, 0);
            zim[nt] = __builtin_amdgcn_mfma_f32_16x16x32_bf16(Cl, Yih, zim[nt], 0, 0, 0);
            zim[nt] = __builtin_amdgcn_mfma_f32_16x16x32_bf16(Nh, Yrh, zim[nt], 0, 0, 0);
            zim[nt] = __builtin_amdgcn_mfma_f32_16x16x32_bf16(Nh, Yrl, zim[nt], 0, 0, 0);
            zim[nt] = __builtin_amdgcn_mfma_f32_16x16x32_bf16(Nl, Yrh, zim[nt], 0, 0, 0);
        }
    }
    float2* __restrict__ op = xft + (size_t)blockIdx.x * (NM * NKX);
    #pragma unroll
    for (int nt = 0; nt < 2; ++nt) {
        const int kx = nt * 16 + l15;
        #pragma unroll
        for (int r = 0; r < 4; ++r) {
            const int m = wv * 16 + lk * 4 + r;
            op[m * NKX + kx] = make_float2(zre[nt][r] * INV256, zim[nt][r] * INV256);
        }
    }
}

// ---------------- Kernel 2: per-mode channel contraction (v5) ----------------
// grid = (m=64, og=4, kh=8), 256 threads, 4 kx per block -> 8 blocks/CU.
// Same v3 pipeline: compute(i) -> LDS-write(i+1) -> barrier -> issue load(i+3).
// Wave0 loads x (64 slots), wave1 loads w (64 slots); waves 2-3 compute-only.
__global__ __launch_bounds__(256) void mode_v5(const float2* __restrict__ xft,
                                               const int* __restrict__ q1,
                                               const int* __restrict__ q2,
                                               const float* __restrict__ w1s,
                                               const float* __restrict__ w1m,
                                               const float* __restrict__ w2s,
                                               const float* __restrict__ w2m,
                                               float2* __restrict__ oft) {
    __shared__ float2 xs[2][16][4];     // [buf][b][kx] — reads broadcast
    __shared__ float2 ws[2][16][5];     // [buf][o][kx] pad-5 -> conflict-free reads
    const int m  = blockIdx.x;          // 0..63
    const int og = blockIdx.y;          // 0..3
    const int kh = blockIdx.z;          // 0..7
    const int t = threadIdx.x;
    const int b = t >> 4, o = t & 15;
    const int mm = (m < 32) ? m : (m - 32);
    const int2* __restrict__ qp = (const int2*)((m < 32) ? q1 : q2);
    const float scale = (m < 32) ? w1s[0] : w2s[0];
    const float wmin  = (m < 32) ? w1m[0] : w2m[0];

    const bool isx = t < 64;            // wave 0
    const bool isw = (t >= 64) && (t < 128);   // wave 1
    const int r8 = (t & 63) >> 2;       // 0..15 (b for x-loaders, o for w-loaders)
    const int k4 = t & 3;               // 0..3 (kx within this kh group)

    const float2* __restrict__ xsrc = xft + (size_t)(r8 * 64) * (NM * NKX)
                                          + m * NKX + kh * 4 + k4;          // += 2048/i
    const int2* __restrict__ wsrc = qp + (size_t)(og * 16 + r8) * 1024
                                       + mm * 32 + kh * 4 + k4;             // += 65536/i

    // prologue: data0 -> LDS[0]; pb <- data1; pa <- data2
    float2 pxa, pxb; int2 pwa, pwb;
    if (isx) {
        xs[0][r8][k4] = xsrc[0];
        pxb = xsrc[(size_t)1 * (NM * NKX)];
        pxa = xsrc[(size_t)2 * (NM * NKX)];
    } else if (isw) {
        const int2 p0 = wsrc[0];
        ws[0][r8][k4] = make_float2(((float)p0.x + 127.0f) * scale + wmin,
                                    ((float)p0.y + 127.0f) * scale + wmin);
        pwb = wsrc[(size_t)1 * 65536];
        pwa = wsrc[(size_t)2 * 65536];
    }
    __syncthreads();

    float accr[4], acci[4];
    #pragma unroll
    for (int k = 0; k < 4; ++k) { accr[k] = 0.f; acci[k] = 0.f; }

    #pragma unroll 1
    for (int j = 0; j < 32; ++j) {
        const int i0 = 2 * j;           // even iter: compute LDS[0], write pb->LDS[1]
        #pragma unroll
        for (int k = 0; k < 4; ++k) {
            const float2 xv = xs[0][b][k];
            const float2 wv = ws[0][o][k];
            accr[k] += xv.x * wv.x - xv.y * wv.y;
            acci[k] += xv.x * wv.y + xv.y * wv.x;
        }
        {   // write data(i0+1)
            if (isx) xs[1][r8][k4] = pxb;
            else if (isw) ws[1][r8][k4] = make_float2(((float)pwb.x + 127.0f) * scale + wmin,
                                                      ((float)pwb.y + 127.0f) * scale + wmin);
            __syncthreads();
            if (i0 + 3 < 64) {
                if (isx) pxb = xsrc[(size_t)(i0 + 3) * (NM * NKX)];
                else if (isw) pwb = wsrc[(size_t)(i0 + 3) * 65536];
            }
        }
        const int i1 = 2 * j + 1;       // odd iter: compute LDS[1], write pa->LDS[0]
        #pragma unroll
        for (int k = 0; k < 4; ++k) {
            const float2 xv = xs[1][b][k];
            const float2 wv = ws[1][o][k];
            accr[k] += xv.x * wv.x - xv.y * wv.y;
            acci[k] += xv.x * wv.y + xv.y * wv.x;
        }
        if (i1 < 63) {                  // write data(i1+1)
            if (isx) xs[0][r8][k4] = pxa;
            else if (isw) ws[0][r8][k4] = make_float2(((float)pwa.x + 127.0f) * scale + wmin,
                                                      ((float)pwa.y + 127.0f) * scale + wmin);
            __syncthreads();
            if (i1 + 3 < 64) {
                if (isx) pxa = xsrc[(size_t)(i1 + 3) * (NM * NKX)];
                else if (isw) pwa = wsrc[(size_t)(i1 + 3) * 65536];
            }
        }
    }

    float2* __restrict__ op = oft + ((size_t)(b * 64 + og * 16 + o) * NM + m) * NKX + kh * 4;
    #pragma unroll
    for (int k = 0; k < 4; ++k) op[k] = make_float2(accr[k], acci[k]);
}

// ---------------- Kernel 3: inverse partial irfft2 via MFMA (round-5 revert) -
// grid = (B*COUT, 2), 256 threads (4 waves). Block handles 128 h rows.
// Phase 4: Z[128h][32kx](re,im) = twiddle[h][m] x O[m][kx]   (K=64)
// Phase 5: out[128h][256w] = Zstack[128h][64kk] x W5[64kk][256w]
// LDS (ushort): OrP @0 [32kx][72], OiP @2304, Zp @4608 [128hl][72]
__global__ __launch_bounds__(256) void inv_mfma(const float2* __restrict__ oft,
                                                const u16* __restrict__ tw2,
                                                float* __restrict__ out) {
    __shared__ u16 lds[13824];   // 27648 B -> 5 blocks/CU
    const int t = threadIdx.x;
    const int lane = t & 63;
    const int wv = t >> 6;
    const int l15 = lane & 15;
    const int lk = lane >> 4;
    const int hh = blockIdx.y;   // 0/1: h half

    const float2* __restrict__ ip = oft + (size_t)blockIdx.x * (NM * NKX);
    #pragma unroll
    for (int r = 0; r < 8; ++r) {
        const int idx = r * 256 + t;
        const int m = idx >> 5, kx = idx & 31;
        const float2 v = ip[idx];
        lds[kx * 72 + m]        = bf16_rtn(v.x);
        lds[2304 + kx * 72 + m] = bf16_rtn(v.y);
    }
    __syncthreads();

    const u16* __restrict__ C4 = tw2;
    const u16* __restrict__ S4 = tw2 + 16384;
    const u16* __restrict__ N4 = tw2 + 32768;

    short8v Br[2][2], Bi[2][2];
    #pragma unroll
    for (int nt = 0; nt < 2; ++nt) {
        #pragma unroll
        for (int kc = 0; kc < 2; ++kc) {
            const int off = (nt * 16 + l15) * 72 + kc * 32 + lk * 8;
            Br[nt][kc] = *(const short8v*)(lds + off);
            Bi[nt][kc] = *(const short8v*)(lds + 2304 + off);
        }
    }

    #pragma unroll
    for (int mt = 0; mt < 2; ++mt) {
        const int lt = wv * 2 + mt;       // local 16-row tile 0..7
        const int HT = hh * 8 + lt;       // global tile 0..15
        f32x4 zr[2] = {f32x4{0,0,0,0}, f32x4{0,0,0,0}};
        f32x4 zi[2] = {f32x4{0,0,0,0}, f32x4{0,0,0,0}};
        #pragma unroll
        for (int kc = 0; kc < 2; ++kc) {
            const int abase = ((HT * 2 + kc) * 64 + lane) * 8;
            const short8v C = *(const short8v*)(C4 + abase);
            const short8v S = *(const short8v*)(S4 + abase);
            const short8v N = *(const short8v*)(N4 + abase);
            #pragma unroll
            for (int nt = 0; nt < 2; ++nt) {
                zr[nt] = __builtin_amdgcn_mfma_f32_16x16x32_bf16(C, Br[nt][kc], zr[nt], 0, 0, 0);
                zr[nt] = __builtin_amdgcn_mfma_f32_16x16x32_bf16(N, Bi[nt][kc], zr[nt], 0, 0, 0);
                zi[nt] = __builtin_amdgcn_mfma_f32_16x16x32_bf16(S, Br[nt][kc], zi[nt], 0, 0, 0);
                zi[nt] = __builtin_amdgcn_mfma_f32_16x16x32_bf16(C, Bi[nt][kc], zi[nt], 0, 0, 0);
            }
        }
        #pragma unroll
        for (int nt = 0; nt < 2; ++nt) {
            const int kx = nt * 16 + l15;
            #pragma unroll
            for (int r = 0; r < 4; ++r) {
                const int hl = lt * 16 + lk * 4 + r;
                const u32 pk = (u32)bf16_rtn(zr[nt][r]) | ((u32)bf16_rtn(zi[nt][r]) << 16);
                *(u32*)(lds + 4608 + hl * 72 + 2 * kx) = pk;
            }
        }
    }
    __syncthreads();

    const u16* __restrict__ W5 = tw2 + 49152;
    float* __restrict__ op = out + (size_t)blockIdx.x * (NH * NW) + (size_t)hh * 128 * NW;
    for (int nt = 0; nt < 16; ++nt) {
        const short8v B0 = *(const short8v*)(W5 + ((nt * 2 + 0) * 64 + lane) * 8);
        const short8v B1 = *(const short8v*)(W5 + ((nt * 2 + 1) * 64 + lane) * 8);
        const int w = nt * 16 + l15;
        #pragma unroll
        for (int mt = 0; mt < 2; ++mt) {
            const int lt = wv * 2 + mt;
            const int h0 = lt * 16 + l15;
            const short8v A0 = *(const short8v*)(lds + 4608 + h0 * 72 + lk * 8);
            const short8v A1 = *(const short8v*)(lds + 4608 + h0 * 72 + 32 + lk * 8);
            f32x4 acc = {0, 0, 0, 0};
            acc = __builtin_amdgcn_mfma_f32_16x16x32_bf16(A0, B0, acc, 0, 0, 0);
            acc = __builtin_amdgcn_mfma_f32_16x16x32_bf16(A1, B1, acc, 0, 0, 0);
            #pragma unroll
            for (int r = 0; r < 4; ++r) {
                const int hl = lt * 16 + lk * 4 + r;
                op[hl * 256 + w] = acc[r];
            }
        }
    }
}

extern "C" void kernel_launch(void* const* d_in, const int* in_sizes, int n_in,
                              void* d_out, int out_size, void* d_ws, size_t ws_size,
                              hipStream_t stream) {
    const float* x  = (const float*)d_in[0];
    const int* q1   = (const int*)d_in[1];
    const int* q2   = (const int*)d_in[2];
    const float* w1s = (const float*)d_in[3];
    const float* w1m = (const float*)d_in[4];
    const float* w2s = (const float*)d_in[5];
    const float* w2m = (const float*)d_in[6];
    float* out = (float*)d_out;

    float2* xft = (float2*)d_ws;                          // [0, 16 MiB)
    float2* oft = xft + (size_t)NB * NCIN * NM * NKX;     // [16, 32 MiB)
    u16* tw  = (u16*)((char*)d_ws + (size_t)48 * 1024 * 1024);  // 256 KiB
    u16* tw2 = tw + 131072;                                      // 128 KiB

    init_tw<<<128, 256, 0, stream>>>(tw);
    init_tw2<<<128, 256, 0, stream>>>(tw2);
    fwd_mfma<<<NB * NCIN, 256, 0, stream>>>(x, tw, xft);
    mode_v5<<<dim3(NM, 4, 8), 256, 0, stream>>>(xft, q1, q2, w1s, w1m, w2s, w2m, oft);
    inv_mfma<<<dim3(NB * NCOUT, 2), 256, 0, stream>>>(oft, tw2, out);
}